// Round 2
// baseline (53596.277 us; speedup 1.0000x reference)
//
#include <hip/hip_runtime.h>
#include <hip/hip_bf16.h>

typedef __attribute__((ext_vector_type(4))) float floatx4;
typedef __attribute__((ext_vector_type(8))) short shortx8;

#define NB 64
#define NS 256
#define NU 1024
#define NT 512

__device__ __forceinline__ unsigned short f2bf(float f){
  union{float f;unsigned u;}v; v.f=f;
  unsigned r = v.u + 0x7fffu + ((v.u>>16)&1u);
  return (unsigned short)(r>>16);
}
__device__ __forceinline__ float bf2f(unsigned short h){
  union{unsigned u;float f;}v; v.u = ((unsigned)h)<<16; return v.f;
}
__device__ __forceinline__ float sigf(float x){
  return __builtin_amdgcn_rcpf(1.f + __expf(-x));
}

// ---------------------------------------------------------------------------
// Generic bf16 MFMA GEMM: C[M,N] = A[M,K] * B[K,N] (+bias[col]).
// A: row-major bf16. B: pre-swizzled layout [(nt16*KS+ks)*64+lane]*8 so each
// lane's 16x16x32 B-fragment (n=lane&15, k=quad*8+j) is one 16B load.
// Wave computes a 64x64 tile (4x4 of 16x16).
// MODE 0: fp32 out. MODE 1: bf16 out. MODE 2: fp32 out with row remap
//         r=t*64+b -> orow=b*NS+t (final Y -> d_out).
// ---------------------------------------------------------------------------
template<int MODE>
__global__ void gemm_sw(const unsigned short* __restrict__ A,
                        const unsigned short* __restrict__ Bsw,
                        void* __restrict__ Cout,
                        int M, int N, int K, int ldc,
                        const float* __restrict__ bias)
{
  const int lane = threadIdx.x & 63;
  const int lm = lane & 15, quad = lane >> 4;
  const int nwaves = (gridDim.x * blockDim.x) >> 6;
  const int w = (blockIdx.x * blockDim.x + threadIdx.x) >> 6;
  const int m64 = M >> 6, n64 = N >> 6, KS = K >> 5;
  const int ntask = m64 * n64;
  for (int task = w; task < ntask; task += nwaves) {
    const int mt = task % m64, nt = task / m64;
    floatx4 acc[4][4];
#pragma unroll
    for (int i=0;i<4;i++)
#pragma unroll
      for(int j=0;j<4;j++) acc[i][j] = (floatx4){0.f,0.f,0.f,0.f};
    const unsigned short* Ab = A + (size_t)(mt*64 + lm) * K + quad*8;
    for (int ks=0; ks<KS; ++ks) {
      shortx8 a[4], b[4];
#pragma unroll
      for (int i=0;i<4;i++)
        a[i] = *(const shortx8*)(Ab + (size_t)i*16*K + ks*32);
#pragma unroll
      for (int j=0;j<4;j++)
        b[j] = *(const shortx8*)(Bsw + (((size_t)(nt*4+j)*KS + ks)*64 + lane)*8);
#pragma unroll
      for (int i=0;i<4;i++)
#pragma unroll
        for (int j=0;j<4;j++)
          acc[i][j] = __builtin_amdgcn_mfma_f32_16x16x32_bf16(a[i], b[j], acc[i][j], 0,0,0);
    }
#pragma unroll
    for (int i=0;i<4;i++){
#pragma unroll
      for (int j=0;j<4;j++){
        const int col = nt*64 + j*16 + lm;
        const float bv = bias ? bias[col] : 0.f;
#pragma unroll
        for (int r=0;r<4;r++){
          const int row = mt*64 + i*16 + quad*4 + r;
          const float v = acc[i][j][r] + bv;
          if (MODE==0)      ((float*)Cout)[(size_t)row*ldc + col] = v;
          else if (MODE==1) ((unsigned short*)Cout)[(size_t)row*ldc + col] = f2bf(v);
          else { const int orow = (row&63)*NS + (row>>6);
                 ((float*)Cout)[(size_t)orow*ldc + col] = v; }
        }
      }
    }
  }
}

// ---- prep kernels ----------------------------------------------------------
__global__ void conv_h(const float* __restrict__ src, unsigned short* __restrict__ dst, int n){
  for (int i = blockIdx.x*blockDim.x + threadIdx.x; i < n; i += gridDim.x*blockDim.x)
    dst[i] = f2bf(src[i]);
}

__global__ void conv_misc(const float* __restrict__ Wy2, const float* __restrict__ We2,
                          const float* __restrict__ s0, const float* __restrict__ by1,
                          const float* __restrict__ be1,
                          unsigned short* __restrict__ Wy2A, unsigned short* __restrict__ we2b,
                          unsigned short* __restrict__ s_bf, float* __restrict__ bz)
{
  int i = blockIdx.x*blockDim.x + threadIdx.x;
  if (i < 524288) Wy2A[i] = f2bf(Wy2[i]);
  else if (i < 525312) we2b[i-524288] = f2bf(We2[i-524288]);
  else if (i < 590848) s_bf[i-525312] = f2bf(s0[i-525312]);
  else if (i < 592896) { int n = i - 590848; bz[n] = (n<1024)? by1[n] : be1[n-1024]; }
}

__global__ void vbias_k(const float* __restrict__ by2,
                        const float* __restrict__ bi, const float* __restrict__ bff,
                        const float* __restrict__ bg, const float* __restrict__ bo,
                        const float* __restrict__ Wi, const float* __restrict__ Wf,
                        const float* __restrict__ Wg, const float* __restrict__ Wo,
                        float* __restrict__ vb)
{
  int i = blockIdx.x*blockDim.x + threadIdx.x;
  if (i >= 4096) return;
  int g = i >> 10, u = i & 1023;
  const float* bsrc = (g==0)?bi:(g==1)?bff:(g==2)?bg:bo;
  const float* W    = (g==0)?Wi:(g==1)?Wf:(g==2)?Wg:Wo;
  float s = bsrc[u];
  for (int tt = 0; tt < NT; ++tt) s += by2[tt] * W[(size_t)tt*NU + u];
  vb[i] = s;
}

// pack fp32 row-major (K,N) into swizzled bf16 B-operand layout
__global__ void pack_b(const float* __restrict__ src, unsigned short* __restrict__ dst, int K, int N)
{
  const int KS = K >> 5;
  const size_t total = (size_t)K * N;
  for (size_t i = (size_t)blockIdx.x*blockDim.x + threadIdx.x; i < total;
       i += (size_t)gridDim.x*blockDim.x) {
    int j = i & 7; int lane = (i>>3) & 63; int r = (int)(i >> 9);
    int ks = r % KS; int nt = r / KS;
    int k = ks*32 + (lane>>4)*8 + j;
    int n = nt*16 + (lane&15);
    dst[i] = f2bf(src[(size_t)k*N + n]);
  }
}

// A1 = [Wy1 | We1_s] : K=1024, N=2048
__global__ void pack_a1(const float* __restrict__ Wy1, const float* __restrict__ We1,
                        unsigned short* __restrict__ dst)
{
  const int KS = 32;
  const size_t total = (size_t)1024*2048;
  for (size_t i = (size_t)blockIdx.x*blockDim.x + threadIdx.x; i < total;
       i += (size_t)gridDim.x*blockDim.x) {
    int j = i & 7; int lane = (i>>3) & 63; int r = (int)(i >> 9);
    int ks = r % KS; int nt = r / KS;
    int k = ks*32 + (lane>>4)*8 + j;
    int n = nt*16 + (lane&15);
    float v = (n < 1024) ? Wy1[(size_t)k*1024 + n]
                         : We1[(size_t)(1024+k)*1024 + (n-1024)];
    dst[i] = f2bf(v);
  }
}

// Wbig[2048 x 4096]: k<1024 -> Mg[g][k][u] (g=n>>10,u=n&1023); k>=1024 -> W_g[512+k-1024][u]
__global__ void pack_wbig(const float* __restrict__ Mg,
                          const float* __restrict__ Wi, const float* __restrict__ Wf,
                          const float* __restrict__ Wg, const float* __restrict__ Wo,
                          unsigned short* __restrict__ dst)
{
  const int KS = 64;
  const size_t total = (size_t)2048*4096;
  for (size_t i = (size_t)blockIdx.x*blockDim.x + threadIdx.x; i < total;
       i += (size_t)gridDim.x*blockDim.x) {
    int j = i & 7; int lane = (i>>3) & 63; int r = (int)(i >> 9);
    int ks = r % KS; int nt = r / KS;
    int k = ks*32 + (lane>>4)*8 + j;
    int n = nt*16 + (lane&15);
    int g = n >> 10, u = n & 1023;
    float v;
    if (k < 1024) v = Mg[(size_t)g*1048576 + (size_t)k*1024 + u];
    else {
      const float* W = (g==0)?Wi:(g==1)?Wf:(g==2)?Wg:Wo;
      v = W[(size_t)(512 + k - 1024)*1024 + u];
    }
    dst[i] = f2bf(v);
  }
}

// ---- the sequential recurrence: persistent kernel, hand-rolled grid barrier
// Grid MUST be 256 blocks x 512 threads: 1 block/CU guaranteed co-resident.
struct LoopArgs {
  unsigned short* s_bf;          // (64,1024) bf16 state
  unsigned short* tanh_all;      // (256,64,1024) bf16
  const unsigned short* A1_sw;   // [Wy1|We1_s] swizzled, K=1024,N=2048
  const unsigned short* Wbig_sw; // K=2048,N=4096
  const unsigned short* hproj;   // (64,256,1024) bf16
  const unsigned short* h_bf;    // (64,256,1024) bf16
  const unsigned short* we2b;    // (1024) bf16
  float* qbuf;                   // (64,1024)
  float* watt;                   // (64,256) exp(e)
  float* gates;                  // (64,4096) pre-activation [i|f|g|o]
  const float* bz;               // (2048) [by1|be1]
  const float* vbias;            // (4096)
  const float* be2;              // (1)
  int* bar;                      // [counter, gen] zeroed before launch
};

__global__ void __launch_bounds__(512, 2) loop_kernel(LoopArgs A)
{
  const int tid = threadIdx.x;
  const int bid = blockIdx.x;                 // 256 blocks
  const int wid = tid >> 6;                   // 0..7
  const int lane = tid & 63;
  const int lm = lane & 15, quad = lane >> 4;
  int* bar_cnt = A.bar;
  int* bar_gen = A.bar + 1;

  __shared__ float wsh[256];
  __shared__ float zparts[4];
  __shared__ float cbuf[512][2];

  // device-scope generation barrier (same wbl2/inv semantics as grid.sync)
  auto gsync = [&]() {
    __syncthreads();
    if (tid == 0) {
      __threadfence();   // release: write-back this XCD's L2
      int g = __hip_atomic_load(bar_gen, __ATOMIC_RELAXED, __HIP_MEMORY_SCOPE_AGENT);
      if (__hip_atomic_fetch_add(bar_cnt, 1, __ATOMIC_ACQ_REL, __HIP_MEMORY_SCOPE_AGENT) == 255) {
        __hip_atomic_store(bar_cnt, 0, __ATOMIC_RELAXED, __HIP_MEMORY_SCOPE_AGENT);
        __hip_atomic_store(bar_gen, g + 1, __ATOMIC_RELEASE, __HIP_MEMORY_SCOPE_AGENT);
      } else {
        while (__hip_atomic_load(bar_gen, __ATOMIC_ACQUIRE, __HIP_MEMORY_SCOPE_AGENT) == g)
          __builtin_amdgcn_s_sleep(1);
      }
      __threadfence();   // acquire: invalidate L1 + this XCD's L2
    }
    __syncthreads();
  };

#pragma clang loop unroll(disable)
  for (int t = 0; t < NS; ++t) {
    // -------- P1: z2 = s @ [Wy1|We1_s] + bz -> tanh1 (bf16), q (fp32)
    // 512 tasks spread as 2 waves per block (all 256 CUs active).
    if (wid < 2) {
      const int task = bid*2 + wid;
      const int mt = task & 3, nt = task >> 2;    // 4 m-tiles x 128 n-tiles
      floatx4 acc = (floatx4){0.f,0.f,0.f,0.f};
      const unsigned short* Ab = A.s_bf + (mt*16 + lm)*NU + quad*8;
      for (int ks = 0; ks < 32; ++ks) {
        shortx8 a = *(const shortx8*)(Ab + ks*32);
        shortx8 b = *(const shortx8*)(A.A1_sw + (((size_t)nt*32 + ks)*64 + lane)*8);
        acc = __builtin_amdgcn_mfma_f32_16x16x32_bf16(a, b, acc, 0,0,0);
      }
      const int col = nt*16 + lm;
      const float bzv = A.bz[col];
#pragma unroll
      for (int r = 0; r < 4; ++r) {
        const int row = mt*16 + quad*4 + r;
        const float v = acc[r] + bzv;
        if (col < NU) A.tanh_all[(size_t)t*(NB*NU) + row*NU + col] = f2bf(tanhf(v));
        else          A.qbuf[row*NU + (col - NU)] = v;
      }
    }
    gsync();
    // -------- P2: gates GEMM (waves 0..3) || attention scores (waves 4..7)
    // Co-located on every CU: MFMA pipe + trans pipe overlap (m114).
    if (wid < 4) {
      const int mt = wid, nt = bid;            // block owns nt -> B-slice reused 4x in-CU
      floatx4 acc = (floatx4){0.f,0.f,0.f,0.f};
      const int arow = mt*16 + lm;
      const unsigned short* tA = A.tanh_all + (size_t)t*(NB*NU) + arow*NU + quad*8;
      const unsigned short* sA = A.s_bf + arow*NU + quad*8;
      for (int ks = 0; ks < 32; ++ks) {
        shortx8 a = *(const shortx8*)(tA + ks*32);
        shortx8 b = *(const shortx8*)(A.Wbig_sw + (((size_t)nt*64 + ks)*64 + lane)*8);
        acc = __builtin_amdgcn_mfma_f32_16x16x32_bf16(a, b, acc, 0,0,0);
      }
      for (int ks = 32; ks < 64; ++ks) {
        shortx8 a = *(const shortx8*)(sA + (ks-32)*32);
        shortx8 b = *(const shortx8*)(A.Wbig_sw + (((size_t)nt*64 + ks)*64 + lane)*8);
        acc = __builtin_amdgcn_mfma_f32_16x16x32_bf16(a, b, acc, 0,0,0);
      }
      const int col = nt*16 + lm;
      const float vb = A.vbias[col];
#pragma unroll
      for (int r = 0; r < 4; ++r) {
        const int row = mt*16 + quad*4 + r;
        A.gates[row*4096 + col] = acc[r] + vb;
      }
    } else {
      // attention: aw in [0,1024): wave -> (b, 16 j's). e in (0,1) -> exp w/o max.
      const int aw = bid*4 + (wid - 4);
      const int b = aw >> 4, j0 = (aw & 15) << 4;
      float qv[16], w2[16];
      const float* qp = A.qbuf + b*NU + lane*16;
#pragma unroll
      for (int i = 0; i < 16; ++i) qv[i] = qp[i];
      const unsigned short* w2p = A.we2b + lane*16;
#pragma unroll
      for (int i = 0; i < 16; ++i) w2[i] = bf2f(w2p[i]);
      const float be2v = A.be2[0];
      for (int jj = 0; jj < 16; ++jj) {
        const int j = j0 + jj;
        const unsigned short* hp = A.hproj + ((size_t)(b*NS + j))*NU + lane*16;
        float dot = 0.f;
#pragma unroll
        for (int i = 0; i < 16; ++i) {
          const float x = bf2f(hp[i]) + qv[i];
          dot += w2[i] * __builtin_amdgcn_rcpf(1.f + __expf(-x));
        }
#pragma unroll
        for (int off = 32; off > 0; off >>= 1) dot += __shfl_down(dot, off, 64);
        if (lane == 0) {
          const float e = 1.f/(1.f + __expf(-(dot + be2v)));
          A.watt[b*NS + j] = __expf(e);
        }
      }
    }
    gsync();
    // -------- P3: softmax-normalize + context c + LSTM elementwise -> s_next
    {
      const int b = bid >> 2, uc = (bid & 3) << 8;  // 256 blocks = 64 b x 4 u-chunks(256)
      if (tid < 256) wsh[tid] = A.watt[b*NS + tid];
      __syncthreads();
      if (wid < 4) {
        float z = wsh[wid*64 + lane];
#pragma unroll
        for (int off = 32; off > 0; off >>= 1) z += __shfl_down(z, off, 64);
        if (lane == 0) zparts[wid] = z;
      }
      __syncthreads();
      const float invZ = __builtin_amdgcn_rcpf(zparts[0]+zparts[1]+zparts[2]+zparts[3]);
      const int u = uc + (tid & 127)*2;
      const int js = (tid >> 7) << 6;
      float c0 = 0.f, c1 = 0.f;
      const unsigned short* hb = A.h_bf + (size_t)b*NS*NU;
      for (int jj = 0; jj < 64; ++jj) {
        const int j = js + jj;
        const unsigned int hv = *(const unsigned int*)(hb + (size_t)j*NU + u);
        const float wv = wsh[j];
        c0 += wv * bf2f((unsigned short)(hv & 0xffffu));
        c1 += wv * bf2f((unsigned short)(hv >> 16));
      }
      cbuf[tid][0] = c0; cbuf[tid][1] = c1;
      __syncthreads();
      if (tid < 128) {
        float cc0 = cbuf[tid][0] + cbuf[tid+128][0] + cbuf[tid+256][0] + cbuf[tid+384][0];
        float cc1 = cbuf[tid][1] + cbuf[tid+128][1] + cbuf[tid+256][1] + cbuf[tid+384][1];
        cc0 *= invZ; cc1 *= invZ;
        const int uu = uc + tid*2;
        const float* gp = A.gates + b*4096;
#pragma unroll
        for (int p = 0; p < 2; ++p) {
          const int ux = uu + p;
          const float cx = p ? cc1 : cc0;
          const float iv = sigf(gp[ux]);
          const float fv = sigf(gp[NU + ux]);
          const float gv = tanhf(gp[2*NU + ux]);
          const float ov = sigf(gp[3*NU + ux]);
          const float cn = fv*cx + iv*gv;
          const float sn = ov * tanhf(cn);
          A.s_bf[b*NU + ux] = f2bf(sn);
        }
      }
    }
    gsync();
  }
}

// ---------------------------------------------------------------------------
extern "C" void kernel_launch(void* const* d_in, const int* in_sizes, int n_in,
                              void* d_out, int out_size, void* d_ws, size_t ws_size,
                              hipStream_t stream)
{
  const float* h   = (const float*)d_in[0];
  const float* s0  = (const float*)d_in[1];
  const float* Wy1 = (const float*)d_in[2];
  const float* by1 = (const float*)d_in[3];
  const float* Wy2 = (const float*)d_in[4];
  const float* by2 = (const float*)d_in[5];
  const float* We1 = (const float*)d_in[6];
  const float* be1 = (const float*)d_in[7];
  const float* We2 = (const float*)d_in[8];
  const float* be2 = (const float*)d_in[9];
  const float* Wf_p = (const float*)d_in[10];
  const float* bf_p = (const float*)d_in[11];
  const float* Wi_p = (const float*)d_in[12];
  const float* bi_p = (const float*)d_in[13];
  const float* Wg_p = (const float*)d_in[14];
  const float* bg_p = (const float*)d_in[15];
  const float* Wo_p = (const float*)d_in[16];
  const float* bo_p = (const float*)d_in[17];
  (void)in_sizes; (void)n_in; (void)out_size; (void)ws_size;

  char* ws = (char*)d_ws;
  size_t off = 0;
  auto alloc = [&](size_t bytes)->char*{
    char* p = ws + off; off = (off + bytes + 255) & ~(size_t)255; return p;
  };
  unsigned short* h_bf    = (unsigned short*)alloc((size_t)NB*NS*NU*2);   // 33.5 MB
  unsigned short* hproj   = (unsigned short*)alloc((size_t)NB*NS*NU*2);   // 33.5 MB
  unsigned short* tanh_all= (unsigned short*)alloc((size_t)NS*NB*NU*2);   // 33.5 MB
  unsigned short* A1_sw   = (unsigned short*)alloc((size_t)NU*2048*2);    // 4.2 MB
  unsigned short* Wbig_sw = (unsigned short*)alloc((size_t)2048*4096*2);  // 16.8 MB
  unsigned short* We1h_sw = (unsigned short*)alloc((size_t)NU*NU*2);      // 2.1 MB
  unsigned short* Wy2_sw  = (unsigned short*)alloc((size_t)NU*NT*2);      // 1.05 MB
  unsigned short* we2b = (unsigned short*)alloc(NU*2);
  unsigned short* s_bf = (unsigned short*)alloc(NB*NU*2);
  float* qbuf  = (float*)alloc((size_t)NB*NU*4);
  float* watt  = (float*)alloc((size_t)NB*NS*4);
  float* gates = (float*)alloc((size_t)NB*4096*4);
  float* bz    = (float*)alloc(2048*4);
  float* vbias = (float*)alloc(4096*4);
  int*   bar   = (int*)alloc(256);
  // prep-only buffers aliased into regions not yet written at their use time:
  float* Mg = (float*)tanh_all;                    // 16.8 MB, dead before loop
  unsigned short* Wy2A    = hproj;                 // dead before hproj GEMM
  unsigned short* Wgtop_sw= hproj + (size_t)NU*NT; // 4 MB, dead before hproj GEMM
  // total ~125 MB of d_ws

  hipMemsetAsync(bar, 0, 16, stream);

  conv_h<<<dim3(4096), dim3(256), 0, stream>>>(h, h_bf, NB*NS*NU);
  conv_misc<<<dim3(2316), dim3(256), 0, stream>>>(Wy2, We2, s0, by1, be1, Wy2A, we2b, s_bf, bz);
  vbias_k<<<dim3(16), dim3(256), 0, stream>>>(by2, bi_p, bf_p, bg_p, bo_p,
                                              Wi_p, Wf_p, Wg_p, Wo_p, vbias);
  pack_b<<<dim3(1024), dim3(256), 0, stream>>>(We1, We1h_sw, 1024, 1024);   // We1_h
  pack_b<<<dim3(1024), dim3(256), 0, stream>>>(Wy2, Wy2_sw, 1024, 512);
  pack_b<<<dim3(512), dim3(256), 0, stream>>>(Wi_p, Wgtop_sw + 0*((size_t)NT*NU), 512, 1024);
  pack_b<<<dim3(512), dim3(256), 0, stream>>>(Wf_p, Wgtop_sw + 1*((size_t)NT*NU), 512, 1024);
  pack_b<<<dim3(512), dim3(256), 0, stream>>>(Wg_p, Wgtop_sw + 2*((size_t)NT*NU), 512, 1024);
  pack_b<<<dim3(512), dim3(256), 0, stream>>>(Wo_p, Wgtop_sw + 3*((size_t)NT*NU), 512, 1024);
  pack_a1<<<dim3(1024), dim3(256), 0, stream>>>(Wy1, We1, A1_sw);

  // Mg[g] = Wy2 @ W_g[:512]   (M=1024, N=1024, K=512)
  for (int g = 0; g < 4; ++g)
    gemm_sw<0><<<dim3(1024), dim3(256), 0, stream>>>(
        Wy2A, Wgtop_sw + (size_t)g*(NT*NU), Mg + (size_t)g*NU*NU,
        1024, 1024, 512, 1024, nullptr);
  pack_wbig<<<dim3(2048), dim3(256), 0, stream>>>(Mg, Wi_p, Wf_p, Wg_p, Wo_p, Wbig_sw);

  // h_proj = h @ We1_h -> bf16 (M=16384,N=1024,K=1024); overwrites Wy2A/Wgtop region
  gemm_sw<1><<<dim3(1024), dim3(256), 0, stream>>>(
      h_bf, We1h_sw, hproj, NB*NS, 1024, 1024, 1024, nullptr);

  // the 256-step recurrence: persistent kernel, 256 blocks (1/CU), 3 syncs/step
  LoopArgs la;
  la.s_bf = s_bf; la.tanh_all = tanh_all; la.A1_sw = A1_sw; la.Wbig_sw = Wbig_sw;
  la.hproj = hproj; la.h_bf = h_bf; la.we2b = we2b;
  la.qbuf = qbuf; la.watt = watt; la.gates = gates;
  la.bz = bz; la.vbias = vbias; la.be2 = be2; la.bar = bar;
  loop_kernel<<<dim3(256), dim3(512), 0, stream>>>(la);

  // Y = Tanh1_all @ Wy2 + by2, remapped (t,b)->(b,t) into d_out (M=16384,N=512,K=1024)
  gemm_sw<2><<<dim3(1024), dim3(256), 0, stream>>>(
      tanh_all, Wy2_sw, d_out, NB*NS, 512, 1024, 512, by2);
}

// Round 3
// 31715.802 us; speedup vs baseline: 1.6899x; 1.6899x over previous
//
#include <hip/hip_runtime.h>
#include <hip/hip_bf16.h>

typedef __attribute__((ext_vector_type(4))) float floatx4;
typedef __attribute__((ext_vector_type(8))) short shortx8;

#define NB 64
#define NS 256
#define NU 1024
#define NT 512

__device__ __forceinline__ unsigned short f2bf(float f){
  union{float f;unsigned u;}v; v.f=f;
  unsigned r = v.u + 0x7fffu + ((v.u>>16)&1u);
  return (unsigned short)(r>>16);
}
__device__ __forceinline__ float bf2f(unsigned short h){
  union{unsigned u;float f;}v; v.u = ((unsigned)h)<<16; return v.f;
}
__device__ __forceinline__ float sigf(float x){
  return __builtin_amdgcn_rcpf(1.f + __expf(-x));
}

// ---------------------------------------------------------------------------
// Generic bf16 MFMA GEMM: C[M,N] = A[M,K] * B[K,N] (+bias[col]).
// A: row-major bf16. B: pre-swizzled layout [(nt16*KS+ks)*64+lane]*8 so each
// lane's 16x16x32 B-fragment (n=lane&15, k=quad*8+j) is one 16B load.
// Wave computes a 64x64 tile (4x4 of 16x16).
// MODE 0: fp32 out. MODE 1: bf16 out. MODE 2: fp32 out with row remap
//         r=t*64+b -> orow=b*NS+t (final Y -> d_out).
// ---------------------------------------------------------------------------
template<int MODE>
__global__ void gemm_sw(const unsigned short* __restrict__ A,
                        const unsigned short* __restrict__ Bsw,
                        void* __restrict__ Cout,
                        int M, int N, int K, int ldc,
                        const float* __restrict__ bias)
{
  const int lane = threadIdx.x & 63;
  const int lm = lane & 15, quad = lane >> 4;
  const int nwaves = (gridDim.x * blockDim.x) >> 6;
  const int w = (blockIdx.x * blockDim.x + threadIdx.x) >> 6;
  const int m64 = M >> 6, n64 = N >> 6, KS = K >> 5;
  const int ntask = m64 * n64;
  for (int task = w; task < ntask; task += nwaves) {
    const int mt = task % m64, nt = task / m64;
    floatx4 acc[4][4];
#pragma unroll
    for (int i=0;i<4;i++)
#pragma unroll
      for(int j=0;j<4;j++) acc[i][j] = (floatx4){0.f,0.f,0.f,0.f};
    const unsigned short* Ab = A + (size_t)(mt*64 + lm) * K + quad*8;
    for (int ks=0; ks<KS; ++ks) {
      shortx8 a[4], b[4];
#pragma unroll
      for (int i=0;i<4;i++)
        a[i] = *(const shortx8*)(Ab + (size_t)i*16*K + ks*32);
#pragma unroll
      for (int j=0;j<4;j++)
        b[j] = *(const shortx8*)(Bsw + (((size_t)(nt*4+j)*KS + ks)*64 + lane)*8);
#pragma unroll
      for (int i=0;i<4;i++)
#pragma unroll
        for (int j=0;j<4;j++)
          acc[i][j] = __builtin_amdgcn_mfma_f32_16x16x32_bf16(a[i], b[j], acc[i][j], 0,0,0);
    }
#pragma unroll
    for (int i=0;i<4;i++){
#pragma unroll
      for (int j=0;j<4;j++){
        const int col = nt*64 + j*16 + lm;
        const float bv = bias ? bias[col] : 0.f;
#pragma unroll
        for (int r=0;r<4;r++){
          const int row = mt*64 + i*16 + quad*4 + r;
          const float v = acc[i][j][r] + bv;
          if (MODE==0)      ((float*)Cout)[(size_t)row*ldc + col] = v;
          else if (MODE==1) ((unsigned short*)Cout)[(size_t)row*ldc + col] = f2bf(v);
          else { const int orow = (row&63)*NS + (row>>6);
                 ((float*)Cout)[(size_t)orow*ldc + col] = v; }
        }
      }
    }
  }
}

// ---- prep kernels ----------------------------------------------------------
__global__ void conv_h(const float* __restrict__ src, unsigned short* __restrict__ dst, int n){
  for (int i = blockIdx.x*blockDim.x + threadIdx.x; i < n; i += gridDim.x*blockDim.x)
    dst[i] = f2bf(src[i]);
}

__global__ void conv_misc(const float* __restrict__ Wy2, const float* __restrict__ We2,
                          const float* __restrict__ s0, const float* __restrict__ by1,
                          const float* __restrict__ be1,
                          unsigned short* __restrict__ Wy2A, unsigned short* __restrict__ we2b,
                          unsigned short* __restrict__ s_bf, float* __restrict__ bz)
{
  int i = blockIdx.x*blockDim.x + threadIdx.x;
  if (i < 524288) Wy2A[i] = f2bf(Wy2[i]);
  else if (i < 525312) we2b[i-524288] = f2bf(We2[i-524288]);
  else if (i < 590848) s_bf[i-525312] = f2bf(s0[i-525312]);
  else if (i < 592896) { int n = i - 590848; bz[n] = (n<1024)? by1[n] : be1[n-1024]; }
}

__global__ void vbias_k(const float* __restrict__ by2,
                        const float* __restrict__ bi, const float* __restrict__ bff,
                        const float* __restrict__ bg, const float* __restrict__ bo,
                        const float* __restrict__ Wi, const float* __restrict__ Wf,
                        const float* __restrict__ Wg, const float* __restrict__ Wo,
                        float* __restrict__ vb)
{
  int i = blockIdx.x*blockDim.x + threadIdx.x;
  if (i >= 4096) return;
  int g = i >> 10, u = i & 1023;
  const float* bsrc = (g==0)?bi:(g==1)?bff:(g==2)?bg:bo;
  const float* W    = (g==0)?Wi:(g==1)?Wf:(g==2)?Wg:Wo;
  float s = bsrc[u];
  for (int tt = 0; tt < NT; ++tt) s += by2[tt] * W[(size_t)tt*NU + u];
  vb[i] = s;
}

// pack fp32 row-major (K,N) into swizzled bf16 B-operand layout
__global__ void pack_b(const float* __restrict__ src, unsigned short* __restrict__ dst, int K, int N)
{
  const int KS = K >> 5;
  const size_t total = (size_t)K * N;
  for (size_t i = (size_t)blockIdx.x*blockDim.x + threadIdx.x; i < total;
       i += (size_t)gridDim.x*blockDim.x) {
    int j = i & 7; int lane = (i>>3) & 63; int r = (int)(i >> 9);
    int ks = r % KS; int nt = r / KS;
    int k = ks*32 + (lane>>4)*8 + j;
    int n = nt*16 + (lane&15);
    dst[i] = f2bf(src[(size_t)k*N + n]);
  }
}

// A1 = [Wy1 | We1_s] : K=1024, N=2048
__global__ void pack_a1(const float* __restrict__ Wy1, const float* __restrict__ We1,
                        unsigned short* __restrict__ dst)
{
  const int KS = 32;
  const size_t total = (size_t)1024*2048;
  for (size_t i = (size_t)blockIdx.x*blockDim.x + threadIdx.x; i < total;
       i += (size_t)gridDim.x*blockDim.x) {
    int j = i & 7; int lane = (i>>3) & 63; int r = (int)(i >> 9);
    int ks = r % KS; int nt = r / KS;
    int k = ks*32 + (lane>>4)*8 + j;
    int n = nt*16 + (lane&15);
    float v = (n < 1024) ? Wy1[(size_t)k*1024 + n]
                         : We1[(size_t)(1024+k)*1024 + (n-1024)];
    dst[i] = f2bf(v);
  }
}

// Wbig[2048 x 4096]: k<1024 -> Mg[g][k][u] (g=n>>10,u=n&1023); k>=1024 -> W_g[512+k-1024][u]
__global__ void pack_wbig(const float* __restrict__ Mg,
                          const float* __restrict__ Wi, const float* __restrict__ Wf,
                          const float* __restrict__ Wg, const float* __restrict__ Wo,
                          unsigned short* __restrict__ dst)
{
  const int KS = 64;
  const size_t total = (size_t)2048*4096;
  for (size_t i = (size_t)blockIdx.x*blockDim.x + threadIdx.x; i < total;
       i += (size_t)gridDim.x*blockDim.x) {
    int j = i & 7; int lane = (i>>3) & 63; int r = (int)(i >> 9);
    int ks = r % KS; int nt = r / KS;
    int k = ks*32 + (lane>>4)*8 + j;
    int n = nt*16 + (lane&15);
    int g = n >> 10, u = n & 1023;
    float v;
    if (k < 1024) v = Mg[(size_t)g*1048576 + (size_t)k*1024 + u];
    else {
      const float* W = (g==0)?Wi:(g==1)?Wf:(g==2)?Wg:Wo;
      v = W[(size_t)(512 + k - 1024)*1024 + u];
    }
    dst[i] = f2bf(v);
  }
}

// ---- the sequential recurrence: persistent kernel, hand-rolled grid barrier
// Grid MUST be 256 blocks x 512 threads: 1 block/CU guaranteed co-resident.
struct LoopArgs {
  unsigned short* s_bf;          // (64,1024) bf16 state
  unsigned short* tanh_all;      // (256,64,1024) bf16
  const unsigned short* A1_sw;   // [Wy1|We1_s] swizzled, K=1024,N=2048
  const unsigned short* Wbig_sw; // K=2048,N=4096
  const unsigned short* hproj;   // (64,256,1024) bf16
  const unsigned short* h_bf;    // (64,256,1024) bf16
  const unsigned short* we2b;    // (1024) bf16
  float* qbuf;                   // (64,1024)
  float* watt;                   // (64,256) exp(e)
  float* gates;                  // (64,4096) pre-activation [i|f|g|o]
  const float* bz;               // (2048) [by1|be1]
  const float* vbias;            // (4096)
  const float* be2;              // (1)
  int* bar;                      // [counter, gen] zeroed before launch
};

__global__ void __launch_bounds__(512, 2) loop_kernel(LoopArgs A)
{
  const int tid = threadIdx.x;
  const int bid = blockIdx.x;                 // 256 blocks
  const int wid = tid >> 6;                   // 0..7
  const int lane = tid & 63;
  const int lm = lane & 15, quad = lane >> 4;
  int* bar_cnt = A.bar;
  int* bar_gen = A.bar + 16;                  // separate cacheline from cnt

  __shared__ float wsh[256];
  __shared__ float zparts[4];
  __shared__ float cbuf[512][2];

  // Two-fence device barrier. Arrive/poll are RELAXED agent-scope atomics
  // (these bypass the non-coherent L2 levels on gfx95x, so relaxed polling
  // observes the flip); exactly ONE release fence before arrive and ONE
  // acquire fence after the flip — O(blocks) cache maintenance per barrier
  // instead of O(poll-iters * blocks) from ACQUIRE-per-poll (R2: 65us/sync).
  auto gsync = [&]() {
    __syncthreads();
    if (tid == 0) {
      __builtin_amdgcn_fence(__ATOMIC_RELEASE, "agent");   // wbl2: publish our writes
      int g = __hip_atomic_load(bar_gen, __ATOMIC_RELAXED, __HIP_MEMORY_SCOPE_AGENT);
      int a = __hip_atomic_fetch_add(bar_cnt, 1, __ATOMIC_RELAXED, __HIP_MEMORY_SCOPE_AGENT);
      if (a == 255) {
        __hip_atomic_store(bar_cnt, 0, __ATOMIC_RELAXED, __HIP_MEMORY_SCOPE_AGENT);
        __hip_atomic_store(bar_gen, g + 1, __ATOMIC_RELAXED, __HIP_MEMORY_SCOPE_AGENT);
      } else {
        while (__hip_atomic_load(bar_gen, __ATOMIC_RELAXED, __HIP_MEMORY_SCOPE_AGENT) == g)
          __builtin_amdgcn_s_sleep(2);
      }
      __builtin_amdgcn_fence(__ATOMIC_ACQUIRE, "agent");   // inv: see others' writes
    }
    __syncthreads();
  };

#pragma clang loop unroll(disable)
  for (int t = 0; t < NS; ++t) {
    // -------- P1: z2 = s @ [Wy1|We1_s] + bz -> tanh1 (bf16), q (fp32)
    // 512 tasks spread as 2 waves per block (all 256 CUs active).
    if (wid < 2) {
      const int task = bid*2 + wid;
      const int mt = task & 3, nt = task >> 2;    // 4 m-tiles x 128 n-tiles
      floatx4 acc = (floatx4){0.f,0.f,0.f,0.f};
      const unsigned short* Ab = A.s_bf + (mt*16 + lm)*NU + quad*8;
      for (int ks = 0; ks < 32; ++ks) {
        shortx8 a = *(const shortx8*)(Ab + ks*32);
        shortx8 b = *(const shortx8*)(A.A1_sw + (((size_t)nt*32 + ks)*64 + lane)*8);
        acc = __builtin_amdgcn_mfma_f32_16x16x32_bf16(a, b, acc, 0,0,0);
      }
      const int col = nt*16 + lm;
      const float bzv = A.bz[col];
#pragma unroll
      for (int r = 0; r < 4; ++r) {
        const int row = mt*16 + quad*4 + r;
        const float v = acc[r] + bzv;
        if (col < NU) A.tanh_all[(size_t)t*(NB*NU) + row*NU + col] = f2bf(tanhf(v));
        else          A.qbuf[row*NU + (col - NU)] = v;
      }
    }
    gsync();
    // -------- P2: gates GEMM (waves 0..3) || attention scores (waves 4..7)
    // Co-located on every CU: MFMA pipe + trans pipe overlap (m114).
    if (wid < 4) {
      const int mt = wid, nt = bid;            // block owns nt -> B-slice reused 4x in-CU
      floatx4 acc = (floatx4){0.f,0.f,0.f,0.f};
      const int arow = mt*16 + lm;
      const unsigned short* tA = A.tanh_all + (size_t)t*(NB*NU) + arow*NU + quad*8;
      const unsigned short* sA = A.s_bf + arow*NU + quad*8;
      for (int ks = 0; ks < 32; ++ks) {
        shortx8 a = *(const shortx8*)(tA + ks*32);
        shortx8 b = *(const shortx8*)(A.Wbig_sw + (((size_t)nt*64 + ks)*64 + lane)*8);
        acc = __builtin_amdgcn_mfma_f32_16x16x32_bf16(a, b, acc, 0,0,0);
      }
      for (int ks = 32; ks < 64; ++ks) {
        shortx8 a = *(const shortx8*)(sA + (ks-32)*32);
        shortx8 b = *(const shortx8*)(A.Wbig_sw + (((size_t)nt*64 + ks)*64 + lane)*8);
        acc = __builtin_amdgcn_mfma_f32_16x16x32_bf16(a, b, acc, 0,0,0);
      }
      const int col = nt*16 + lm;
      const float vb = A.vbias[col];
#pragma unroll
      for (int r = 0; r < 4; ++r) {
        const int row = mt*16 + quad*4 + r;
        A.gates[row*4096 + col] = acc[r] + vb;
      }
    } else {
      // attention: aw in [0,1024): wave -> (b, 16 j's). e in (0,1) -> exp w/o max.
      const int aw = bid*4 + (wid - 4);
      const int b = aw >> 4, j0 = (aw & 15) << 4;
      float qv[16], w2[16];
      const float* qp = A.qbuf + b*NU + lane*16;
#pragma unroll
      for (int i = 0; i < 16; ++i) qv[i] = qp[i];
      const unsigned short* w2p = A.we2b + lane*16;
#pragma unroll
      for (int i = 0; i < 16; ++i) w2[i] = bf2f(w2p[i]);
      const float be2v = A.be2[0];
      for (int jj = 0; jj < 16; ++jj) {
        const int j = j0 + jj;
        const unsigned short* hp = A.hproj + ((size_t)(b*NS + j))*NU + lane*16;
        float dot = 0.f;
#pragma unroll
        for (int i = 0; i < 16; ++i) {
          const float x = bf2f(hp[i]) + qv[i];
          dot += w2[i] * __builtin_amdgcn_rcpf(1.f + __expf(-x));
        }
#pragma unroll
        for (int off = 32; off > 0; off >>= 1) dot += __shfl_down(dot, off, 64);
        if (lane == 0) {
          const float e = 1.f/(1.f + __expf(-(dot + be2v)));
          A.watt[b*NS + j] = __expf(e);
        }
      }
    }
    gsync();
    // -------- P3: softmax-normalize + context c + LSTM elementwise -> s_next
    {
      const int b = bid >> 2, uc = (bid & 3) << 8;  // 256 blocks = 64 b x 4 u-chunks(256)
      if (tid < 256) wsh[tid] = A.watt[b*NS + tid];
      __syncthreads();
      if (wid < 4) {
        float z = wsh[wid*64 + lane];
#pragma unroll
        for (int off = 32; off > 0; off >>= 1) z += __shfl_down(z, off, 64);
        if (lane == 0) zparts[wid] = z;
      }
      __syncthreads();
      const float invZ = __builtin_amdgcn_rcpf(zparts[0]+zparts[1]+zparts[2]+zparts[3]);
      const int u = uc + (tid & 127)*2;
      const int js = (tid >> 7) << 6;
      float c0 = 0.f, c1 = 0.f;
      const unsigned short* hb = A.h_bf + (size_t)b*NS*NU;
      for (int jj = 0; jj < 64; ++jj) {
        const int j = js + jj;
        const unsigned int hv = *(const unsigned int*)(hb + (size_t)j*NU + u);
        const float wv = wsh[j];
        c0 += wv * bf2f((unsigned short)(hv & 0xffffu));
        c1 += wv * bf2f((unsigned short)(hv >> 16));
      }
      cbuf[tid][0] = c0; cbuf[tid][1] = c1;
      __syncthreads();
      if (tid < 128) {
        float cc0 = cbuf[tid][0] + cbuf[tid+128][0] + cbuf[tid+256][0] + cbuf[tid+384][0];
        float cc1 = cbuf[tid][1] + cbuf[tid+128][1] + cbuf[tid+256][1] + cbuf[tid+384][1];
        cc0 *= invZ; cc1 *= invZ;
        const int uu = uc + tid*2;
        const float* gp = A.gates + b*4096;
#pragma unroll
        for (int p = 0; p < 2; ++p) {
          const int ux = uu + p;
          const float cx = p ? cc1 : cc0;
          const float iv = sigf(gp[ux]);
          const float fv = sigf(gp[NU + ux]);
          const float gv = tanhf(gp[2*NU + ux]);
          const float ov = sigf(gp[3*NU + ux]);
          const float cn = fv*cx + iv*gv;
          const float sn = ov * tanhf(cn);
          A.s_bf[b*NU + ux] = f2bf(sn);
        }
      }
    }
    gsync();
  }
}

// ---------------------------------------------------------------------------
extern "C" void kernel_launch(void* const* d_in, const int* in_sizes, int n_in,
                              void* d_out, int out_size, void* d_ws, size_t ws_size,
                              hipStream_t stream)
{
  const float* h   = (const float*)d_in[0];
  const float* s0  = (const float*)d_in[1];
  const float* Wy1 = (const float*)d_in[2];
  const float* by1 = (const float*)d_in[3];
  const float* Wy2 = (const float*)d_in[4];
  const float* by2 = (const float*)d_in[5];
  const float* We1 = (const float*)d_in[6];
  const float* be1 = (const float*)d_in[7];
  const float* We2 = (const float*)d_in[8];
  const float* be2 = (const float*)d_in[9];
  const float* Wf_p = (const float*)d_in[10];
  const float* bf_p = (const float*)d_in[11];
  const float* Wi_p = (const float*)d_in[12];
  const float* bi_p = (const float*)d_in[13];
  const float* Wg_p = (const float*)d_in[14];
  const float* bg_p = (const float*)d_in[15];
  const float* Wo_p = (const float*)d_in[16];
  const float* bo_p = (const float*)d_in[17];
  (void)in_sizes; (void)n_in; (void)out_size; (void)ws_size;

  char* ws = (char*)d_ws;
  size_t off = 0;
  auto alloc = [&](size_t bytes)->char*{
    char* p = ws + off; off = (off + bytes + 255) & ~(size_t)255; return p;
  };
  unsigned short* h_bf    = (unsigned short*)alloc((size_t)NB*NS*NU*2);   // 33.5 MB
  unsigned short* hproj   = (unsigned short*)alloc((size_t)NB*NS*NU*2);   // 33.5 MB
  unsigned short* tanh_all= (unsigned short*)alloc((size_t)NS*NB*NU*2);   // 33.5 MB
  unsigned short* A1_sw   = (unsigned short*)alloc((size_t)NU*2048*2);    // 4.2 MB
  unsigned short* Wbig_sw = (unsigned short*)alloc((size_t)2048*4096*2);  // 16.8 MB
  unsigned short* We1h_sw = (unsigned short*)alloc((size_t)NU*NU*2);      // 2.1 MB
  unsigned short* Wy2_sw  = (unsigned short*)alloc((size_t)NU*NT*2);      // 1.05 MB
  unsigned short* we2b = (unsigned short*)alloc(NU*2);
  unsigned short* s_bf = (unsigned short*)alloc(NB*NU*2);
  float* qbuf  = (float*)alloc((size_t)NB*NU*4);
  float* watt  = (float*)alloc((size_t)NB*NS*4);
  float* gates = (float*)alloc((size_t)NB*4096*4);
  float* bz    = (float*)alloc(2048*4);
  float* vbias = (float*)alloc(4096*4);
  int*   bar   = (int*)alloc(256);
  // prep-only buffers aliased into regions not yet written at their use time:
  float* Mg = (float*)tanh_all;                    // 16.8 MB, dead before loop
  unsigned short* Wy2A    = hproj;                 // dead before hproj GEMM
  unsigned short* Wgtop_sw= hproj + (size_t)NU*NT; // 4 MB, dead before hproj GEMM
  // total ~125 MB of d_ws

  hipMemsetAsync(bar, 0, 256, stream);

  conv_h<<<dim3(4096), dim3(256), 0, stream>>>(h, h_bf, NB*NS*NU);
  conv_misc<<<dim3(2316), dim3(256), 0, stream>>>(Wy2, We2, s0, by1, be1, Wy2A, we2b, s_bf, bz);
  vbias_k<<<dim3(16), dim3(256), 0, stream>>>(by2, bi_p, bf_p, bg_p, bo_p,
                                              Wi_p, Wf_p, Wg_p, Wo_p, vbias);
  pack_b<<<dim3(1024), dim3(256), 0, stream>>>(We1, We1h_sw, 1024, 1024);   // We1_h
  pack_b<<<dim3(1024), dim3(256), 0, stream>>>(Wy2, Wy2_sw, 1024, 512);
  pack_b<<<dim3(512), dim3(256), 0, stream>>>(Wi_p, Wgtop_sw + 0*((size_t)NT*NU), 512, 1024);
  pack_b<<<dim3(512), dim3(256), 0, stream>>>(Wf_p, Wgtop_sw + 1*((size_t)NT*NU), 512, 1024);
  pack_b<<<dim3(512), dim3(256), 0, stream>>>(Wg_p, Wgtop_sw + 2*((size_t)NT*NU), 512, 1024);
  pack_b<<<dim3(512), dim3(256), 0, stream>>>(Wo_p, Wgtop_sw + 3*((size_t)NT*NU), 512, 1024);
  pack_a1<<<dim3(1024), dim3(256), 0, stream>>>(Wy1, We1, A1_sw);

  // Mg[g] = Wy2 @ W_g[:512]   (M=1024, N=1024, K=512)
  for (int g = 0; g < 4; ++g)
    gemm_sw<0><<<dim3(1024), dim3(256), 0, stream>>>(
        Wy2A, Wgtop_sw + (size_t)g*(NT*NU), Mg + (size_t)g*NU*NU,
        1024, 1024, 512, 1024, nullptr);
  pack_wbig<<<dim3(2048), dim3(256), 0, stream>>>(Mg, Wi_p, Wf_p, Wg_p, Wo_p, Wbig_sw);

  // h_proj = h @ We1_h -> bf16 (M=16384,N=1024,K=1024); overwrites Wy2A/Wgtop region
  gemm_sw<1><<<dim3(1024), dim3(256), 0, stream>>>(
      h_bf, We1h_sw, hproj, NB*NS, 1024, 1024, 1024, nullptr);

  // the 256-step recurrence: persistent kernel, 256 blocks (1/CU), 3 syncs/step
  LoopArgs la;
  la.s_bf = s_bf; la.tanh_all = tanh_all; la.A1_sw = A1_sw; la.Wbig_sw = Wbig_sw;
  la.hproj = hproj; la.h_bf = h_bf; la.we2b = we2b;
  la.qbuf = qbuf; la.watt = watt; la.gates = gates;
  la.bz = bz; la.vbias = vbias; la.be2 = be2; la.bar = bar;
  loop_kernel<<<dim3(256), dim3(512), 0, stream>>>(la);

  // Y = Tanh1_all @ Wy2 + by2, remapped (t,b)->(b,t) into d_out (M=16384,N=512,K=1024)
  gemm_sw<2><<<dim3(1024), dim3(256), 0, stream>>>(
      tanh_all, Wy2_sw, d_out, NB*NS, 512, 1024, 512, by2);
}

// Round 5
// 17072.603 us; speedup vs baseline: 3.1393x; 1.8577x over previous
//
#include <hip/hip_runtime.h>
#include <hip/hip_bf16.h>

typedef __attribute__((ext_vector_type(4))) float floatx4;
typedef __attribute__((ext_vector_type(2))) float floatx2;
typedef __attribute__((ext_vector_type(8))) short shortx8;

#define NB 64
#define NS 256
#define NU 1024
#define NT 512

__device__ __forceinline__ unsigned short f2bf(float f){
  union{float f;unsigned u;}v; v.f=f;
  unsigned r = v.u + 0x7fffu + ((v.u>>16)&1u);
  return (unsigned short)(r>>16);
}
__device__ __forceinline__ float bf2f(unsigned short h){
  union{unsigned u;float f;}v; v.u = ((unsigned)h)<<16; return v.f;
}
__device__ __forceinline__ float sigf(float x){
  return __builtin_amdgcn_rcpf(1.f + __expf(-x));
}

// ---- coherent (LLC-level, fence-free) access helpers -----------------------
// sc0 sc1 loads/stores bypass L1/L2 and serialize at the Infinity-Cache
// coherence point -> no buffer_wbl2/buffer_inv fences needed, and read-only
// weights/h/hproj stay L2-resident across all 256 steps.
// NOTE: outputs are EARLY-CLOBBER (=&v): the address input is re-read after
// the first output is written (R4 crash: addr pair allocated over an output).
__device__ __forceinline__ void cburst8(shortx8 a[8], const unsigned short* p){
  asm volatile(
    "global_load_dwordx4 %0, %8, off sc0 sc1\n\t"
    "global_load_dwordx4 %1, %8, off offset:64 sc0 sc1\n\t"
    "global_load_dwordx4 %2, %8, off offset:128 sc0 sc1\n\t"
    "global_load_dwordx4 %3, %8, off offset:192 sc0 sc1\n\t"
    "global_load_dwordx4 %4, %8, off offset:256 sc0 sc1\n\t"
    "global_load_dwordx4 %5, %8, off offset:320 sc0 sc1\n\t"
    "global_load_dwordx4 %6, %8, off offset:384 sc0 sc1\n\t"
    "global_load_dwordx4 %7, %8, off offset:448 sc0 sc1\n\t"
    "s_waitcnt vmcnt(0)"
    : "=&v"(a[0]),"=&v"(a[1]),"=&v"(a[2]),"=&v"(a[3]),
      "=&v"(a[4]),"=&v"(a[5]),"=&v"(a[6]),"=&v"(a[7])
    : "v"(p) : "memory");
}
__device__ __forceinline__ void cburst4f(floatx4 a[4], const float* p){
  asm volatile(
    "global_load_dwordx4 %0, %4, off sc0 sc1\n\t"
    "global_load_dwordx4 %1, %4, off offset:16 sc0 sc1\n\t"
    "global_load_dwordx4 %2, %4, off offset:32 sc0 sc1\n\t"
    "global_load_dwordx4 %3, %4, off offset:48 sc0 sc1\n\t"
    "s_waitcnt vmcnt(0)"
    : "=&v"(a[0]),"=&v"(a[1]),"=&v"(a[2]),"=&v"(a[3]) : "v"(p) : "memory");
}
__device__ __forceinline__ void cburst4d2(floatx2 o[4], const float* p0, const float* p1,
                                          const float* p2, const float* p3){
  asm volatile(
    "global_load_dwordx2 %0, %4, off sc0 sc1\n\t"
    "global_load_dwordx2 %1, %5, off sc0 sc1\n\t"
    "global_load_dwordx2 %2, %6, off sc0 sc1\n\t"
    "global_load_dwordx2 %3, %7, off sc0 sc1\n\t"
    "s_waitcnt vmcnt(0)"
    : "=&v"(o[0]),"=&v"(o[1]),"=&v"(o[2]),"=&v"(o[3])
    : "v"(p0),"v"(p1),"v"(p2),"v"(p3) : "memory");
}
__device__ __forceinline__ float cld_f32(const float* p){
  float v;
  asm volatile("global_load_dword %0, %1, off sc0 sc1\n\ts_waitcnt vmcnt(0)"
               : "=&v"(v) : "v"(p) : "memory");
  return v;
}
__device__ __forceinline__ void cst_u16(unsigned short* p, unsigned short v){
  asm volatile("global_store_short %0, %1, off sc0 sc1" :: "v"(p), "v"((unsigned)v) : "memory");
}
__device__ __forceinline__ void cst_f32(float* p, float v){
  asm volatile("global_store_dword %0, %1, off sc0 sc1" :: "v"(p), "v"(v) : "memory");
}
__device__ __forceinline__ void cst_u32(unsigned* p, unsigned v){
  asm volatile("global_store_dword %0, %1, off sc0 sc1" :: "v"(p), "v"(v) : "memory");
}

// ---------------------------------------------------------------------------
// Generic bf16 MFMA GEMM (prep/epilogue; unchanged - known correct).
// ---------------------------------------------------------------------------
template<int MODE>
__global__ void gemm_sw(const unsigned short* __restrict__ A,
                        const unsigned short* __restrict__ Bsw,
                        void* __restrict__ Cout,
                        int M, int N, int K, int ldc,
                        const float* __restrict__ bias)
{
  const int lane = threadIdx.x & 63;
  const int lm = lane & 15, quad = lane >> 4;
  const int nwaves = (gridDim.x * blockDim.x) >> 6;
  const int w = (blockIdx.x * blockDim.x + threadIdx.x) >> 6;
  const int m64 = M >> 6, n64 = N >> 6, KS = K >> 5;
  const int ntask = m64 * n64;
  for (int task = w; task < ntask; task += nwaves) {
    const int mt = task % m64, nt = task / m64;
    floatx4 acc[4][4];
#pragma unroll
    for (int i=0;i<4;i++)
#pragma unroll
      for(int j=0;j<4;j++) acc[i][j] = (floatx4){0.f,0.f,0.f,0.f};
    const unsigned short* Ab = A + (size_t)(mt*64 + lm) * K + quad*8;
    for (int ks=0; ks<KS; ++ks) {
      shortx8 a[4], b[4];
#pragma unroll
      for (int i=0;i<4;i++)
        a[i] = *(const shortx8*)(Ab + (size_t)i*16*K + ks*32);
#pragma unroll
      for (int j=0;j<4;j++)
        b[j] = *(const shortx8*)(Bsw + (((size_t)(nt*4+j)*KS + ks)*64 + lane)*8);
#pragma unroll
      for (int i=0;i<4;i++)
#pragma unroll
        for (int j=0;j<4;j++)
          acc[i][j] = __builtin_amdgcn_mfma_f32_16x16x32_bf16(a[i], b[j], acc[i][j], 0,0,0);
    }
#pragma unroll
    for (int i=0;i<4;i++){
#pragma unroll
      for (int j=0;j<4;j++){
        const int col = nt*64 + j*16 + lm;
        const float bv = bias ? bias[col] : 0.f;
#pragma unroll
        for (int r=0;r<4;r++){
          const int row = mt*64 + i*16 + quad*4 + r;
          const float v = acc[i][j][r] + bv;
          if (MODE==0)      ((float*)Cout)[(size_t)row*ldc + col] = v;
          else if (MODE==1) ((unsigned short*)Cout)[(size_t)row*ldc + col] = f2bf(v);
          else { const int orow = (row&63)*NS + (row>>6);
                 ((float*)Cout)[(size_t)orow*ldc + col] = v; }
        }
      }
    }
  }
}

// ---- prep kernels (unchanged) ---------------------------------------------
__global__ void conv_h(const float* __restrict__ src, unsigned short* __restrict__ dst, int n){
  for (int i = blockIdx.x*blockDim.x + threadIdx.x; i < n; i += gridDim.x*blockDim.x)
    dst[i] = f2bf(src[i]);
}

__global__ void conv_misc(const float* __restrict__ Wy2, const float* __restrict__ We2,
                          const float* __restrict__ s0, const float* __restrict__ by1,
                          const float* __restrict__ be1,
                          unsigned short* __restrict__ Wy2A, unsigned short* __restrict__ we2b,
                          unsigned short* __restrict__ s_bf, float* __restrict__ bz)
{
  int i = blockIdx.x*blockDim.x + threadIdx.x;
  if (i < 524288) Wy2A[i] = f2bf(Wy2[i]);
  else if (i < 525312) we2b[i-524288] = f2bf(We2[i-524288]);
  else if (i < 590848) s_bf[i-525312] = f2bf(s0[i-525312]);
  else if (i < 592896) { int n = i - 590848; bz[n] = (n<1024)? by1[n] : be1[n-1024]; }
}

__global__ void vbias_k(const float* __restrict__ by2,
                        const float* __restrict__ bi, const float* __restrict__ bff,
                        const float* __restrict__ bg, const float* __restrict__ bo,
                        const float* __restrict__ Wi, const float* __restrict__ Wf,
                        const float* __restrict__ Wg, const float* __restrict__ Wo,
                        float* __restrict__ vb)
{
  int i = blockIdx.x*blockDim.x + threadIdx.x;
  if (i >= 4096) return;
  int g = i >> 10, u = i & 1023;
  const float* bsrc = (g==0)?bi:(g==1)?bff:(g==2)?bg:bo;
  const float* W    = (g==0)?Wi:(g==1)?Wf:(g==2)?Wg:Wo;
  float s = bsrc[u];
  for (int tt = 0; tt < NT; ++tt) s += by2[tt] * W[(size_t)tt*NU + u];
  vb[i] = s;
}

__global__ void pack_b(const float* __restrict__ src, unsigned short* __restrict__ dst, int K, int N)
{
  const int KS = K >> 5;
  const size_t total = (size_t)K * N;
  for (size_t i = (size_t)blockIdx.x*blockDim.x + threadIdx.x; i < total;
       i += (size_t)gridDim.x*blockDim.x) {
    int j = i & 7; int lane = (i>>3) & 63; int r = (int)(i >> 9);
    int ks = r % KS; int nt = r / KS;
    int k = ks*32 + (lane>>4)*8 + j;
    int n = nt*16 + (lane&15);
    dst[i] = f2bf(src[(size_t)k*N + n]);
  }
}

__global__ void pack_a1(const float* __restrict__ Wy1, const float* __restrict__ We1,
                        unsigned short* __restrict__ dst)
{
  const int KS = 32;
  const size_t total = (size_t)1024*2048;
  for (size_t i = (size_t)blockIdx.x*blockDim.x + threadIdx.x; i < total;
       i += (size_t)gridDim.x*blockDim.x) {
    int j = i & 7; int lane = (i>>3) & 63; int r = (int)(i >> 9);
    int ks = r % KS; int nt = r / KS;
    int k = ks*32 + (lane>>4)*8 + j;
    int n = nt*16 + (lane&15);
    float v = (n < 1024) ? Wy1[(size_t)k*1024 + n]
                         : We1[(size_t)(1024+k)*1024 + (n-1024)];
    dst[i] = f2bf(v);
  }
}

__global__ void pack_wbig(const float* __restrict__ Mg,
                          const float* __restrict__ Wi, const float* __restrict__ Wf,
                          const float* __restrict__ Wg, const float* __restrict__ Wo,
                          unsigned short* __restrict__ dst)
{
  const int KS = 64;
  const size_t total = (size_t)2048*4096;
  for (size_t i = (size_t)blockIdx.x*blockDim.x + threadIdx.x; i < total;
       i += (size_t)gridDim.x*blockDim.x) {
    int j = i & 7; int lane = (i>>3) & 63; int r = (int)(i >> 9);
    int ks = r % KS; int nt = r / KS;
    int k = ks*32 + (lane>>4)*8 + j;
    int n = nt*16 + (lane&15);
    int g = n >> 10, u = n & 1023;
    float v;
    if (k < 1024) v = Mg[(size_t)g*1048576 + (size_t)k*1024 + u];
    else {
      const float* W = (g==0)?Wi:(g==1)?Wf:(g==2)?Wg:Wo;
      v = W[(size_t)(512 + k - 1024)*1024 + u];
    }
    dst[i] = f2bf(v);
  }
}

// ---- the sequential recurrence: persistent kernel, FENCE-FREE barrier ------
struct LoopArgs {
  unsigned short* s_bf;          // (64,1024) bf16 state          [coherent]
  unsigned short* tanh_all;      // (256,64,1024) bf16            [coherent in loop]
  const unsigned short* A1_sw;   // weights                        [cached]
  const unsigned short* Wbig_sw; // weights                        [cached]
  const unsigned short* hproj;   // (64,256,1024) bf16             [cached]
  const unsigned short* h_bf;    // (64,256,1024) bf16             [cached]
  const unsigned short* we2b;    // (1024) bf16                    [cached]
  float* qbuf;                   // (64,1024)                      [coherent]
  float* watt;                   // (64,256) exp(e)                [coherent]
  float* gates;                  // (64,4096)                      [coherent]
  const float* bz;               // (2048)                         [cached]
  const float* vbias;            // (4096)                         [cached]
  const float* be2;              // (1)                            [cached]
  int* bar;                      // barrier state, zeroed
};

__global__ void __launch_bounds__(512, 2) loop_kernel(LoopArgs A)
{
  const int tid = threadIdx.x;
  const int bid = blockIdx.x;                 // 256 blocks
  const int wid = tid >> 6;                   // 0..7
  const int lane = tid & 63;
  const int lm = lane & 15, quad = lane >> 4;

  // barrier layout (128B-strided counters): gcnt[16], root, gen
  int* gcnt = A.bar;                          // gcnt[g] at A.bar[g*32]
  int* root = A.bar + 16*32;
  int* genp = A.bar + 16*32 + 32;

  __shared__ float wsh[256];
  __shared__ float zparts[4];
  __shared__ float cbuf[512][2];

  // Fence-free device barrier: all cross-block data moves via sc0sc1 (LLC)
  // accesses, so NO buffer_wbl2/buffer_inv is needed. Every wave drains its
  // own (compiler-untracked) asm stores with an explicit vmcnt(0) BEFORE
  // s_barrier so the leader's arrival atomic cannot overtake data stores.
  auto gsync = [&]() {
    asm volatile("s_waitcnt vmcnt(0) lgkmcnt(0)" ::: "memory");
    __syncthreads();
    if (tid == 0) {
      int g = __hip_atomic_load(genp, __ATOMIC_RELAXED, __HIP_MEMORY_SCOPE_AGENT);
      int grp = bid >> 4;
      if (__hip_atomic_fetch_add(&gcnt[grp*32], 1, __ATOMIC_RELAXED, __HIP_MEMORY_SCOPE_AGENT) == 15) {
        __hip_atomic_store(&gcnt[grp*32], 0, __ATOMIC_RELAXED, __HIP_MEMORY_SCOPE_AGENT);
        if (__hip_atomic_fetch_add(root, 1, __ATOMIC_RELAXED, __HIP_MEMORY_SCOPE_AGENT) == 15) {
          __hip_atomic_store(root, 0, __ATOMIC_RELAXED, __HIP_MEMORY_SCOPE_AGENT);
          __hip_atomic_store(genp, g + 1, __ATOMIC_RELAXED, __HIP_MEMORY_SCOPE_AGENT);
        }
      }
      while (__hip_atomic_load(genp, __ATOMIC_RELAXED, __HIP_MEMORY_SCOPE_AGENT) == g)
        __builtin_amdgcn_s_sleep(1);
    }
    __syncthreads();
  };

#pragma clang loop unroll(disable)
  for (int t = 0; t < NS; ++t) {
    // -------- P1: z2 = s @ [Wy1|We1_s] + bz -> tanh1 (bf16), q (fp32)
    if (wid < 2) {
      const int task = bid*2 + wid;
      const int mt = task & 3, nt = task >> 2;    // 4 m-tiles x 128 n-tiles
      floatx4 acc = (floatx4){0.f,0.f,0.f,0.f};
      const unsigned short* Ab = A.s_bf + (mt*16 + lm)*NU + quad*8;
      for (int kb = 0; kb < 4; ++kb) {
        shortx8 a[8]; cburst8(a, Ab + kb*256);
#pragma unroll
        for (int q = 0; q < 8; ++q) {
          shortx8 b = *(const shortx8*)(A.A1_sw + (((size_t)nt*32 + kb*8 + q)*64 + lane)*8);
          acc = __builtin_amdgcn_mfma_f32_16x16x32_bf16(a[q], b, acc, 0,0,0);
        }
      }
      const int col = nt*16 + lm;
      const float bzv = A.bz[col];
#pragma unroll
      for (int r = 0; r < 4; ++r) {
        const int row = mt*16 + quad*4 + r;
        const float v = acc[r] + bzv;
        if (col < NU) cst_u16(A.tanh_all + (size_t)t*(NB*NU) + row*NU + col, f2bf(tanhf(v)));
        else          cst_f32(A.qbuf + row*NU + (col - NU), v);
      }
    }
    gsync();
    // -------- P2: gates GEMM (waves 0..3) || attention scores (waves 4..7)
    if (wid < 4) {
      const int mt = wid, nt = bid;            // block owns nt -> B-slice L2-resident
      floatx4 acc = (floatx4){0.f,0.f,0.f,0.f};
      const int arow = mt*16 + lm;
      const unsigned short* tA = A.tanh_all + (size_t)t*(NB*NU) + arow*NU + quad*8;
      const unsigned short* sA = A.s_bf + arow*NU + quad*8;
      for (int kb = 0; kb < 4; ++kb) {
        shortx8 a[8]; cburst8(a, tA + kb*256);
#pragma unroll
        for (int q = 0; q < 8; ++q) {
          shortx8 b = *(const shortx8*)(A.Wbig_sw + (((size_t)nt*64 + kb*8 + q)*64 + lane)*8);
          acc = __builtin_amdgcn_mfma_f32_16x16x32_bf16(a[q], b, acc, 0,0,0);
        }
      }
      for (int kb = 0; kb < 4; ++kb) {
        shortx8 a[8]; cburst8(a, sA + kb*256);
#pragma unroll
        for (int q = 0; q < 8; ++q) {
          shortx8 b = *(const shortx8*)(A.Wbig_sw + (((size_t)nt*64 + 32 + kb*8 + q)*64 + lane)*8);
          acc = __builtin_amdgcn_mfma_f32_16x16x32_bf16(a[q], b, acc, 0,0,0);
        }
      }
      const int col = nt*16 + lm;
      const float vb = A.vbias[col];
#pragma unroll
      for (int r = 0; r < 4; ++r) {
        const int row = mt*16 + quad*4 + r;
        cst_f32(A.gates + row*4096 + col, acc[r] + vb);
      }
    } else {
      // attention: aw in [0,1024): wave -> (b, 16 j's). e in (0,1) -> exp w/o max.
      const int aw = bid*4 + (wid - 4);
      const int b = aw >> 4, j0 = (aw & 15) << 4;
      floatx4 q4[4];
      cburst4f(q4, A.qbuf + b*NU + lane*16);
      float qv[16], w2[16];
#pragma unroll
      for (int i = 0; i < 16; ++i) qv[i] = q4[i>>2][i&3];
      const unsigned short* w2p = A.we2b + lane*16;
#pragma unroll
      for (int i = 0; i < 16; ++i) w2[i] = bf2f(w2p[i]);
      const float be2v = A.be2[0];
      for (int jj = 0; jj < 16; ++jj) {
        const int j = j0 + jj;
        const unsigned short* hp = A.hproj + ((size_t)(b*NS + j))*NU + lane*16;
        float dot = 0.f;
#pragma unroll
        for (int i = 0; i < 16; ++i) {
          const float x = bf2f(hp[i]) + qv[i];
          dot += w2[i] * __builtin_amdgcn_rcpf(1.f + __expf(-x));
        }
#pragma unroll
        for (int off = 32; off > 0; off >>= 1) dot += __shfl_down(dot, off, 64);
        if (lane == 0) {
          const float e = 1.f/(1.f + __expf(-(dot + be2v)));
          cst_f32(A.watt + b*NS + j, __expf(e));
        }
      }
    }
    gsync();
    // -------- P3: softmax-normalize + context c + LSTM elementwise -> s_next
    {
      const int b = bid >> 2, uc = (bid & 3) << 8;  // 256 blocks = 64 b x 4 u-chunks(256)
      if (tid < 256) wsh[tid] = cld_f32(A.watt + b*NS + tid);
      __syncthreads();
      if (wid < 4) {
        float z = wsh[wid*64 + lane];
#pragma unroll
        for (int off = 32; off > 0; off >>= 1) z += __shfl_down(z, off, 64);
        if (lane == 0) zparts[wid] = z;
      }
      __syncthreads();
      const float invZ = __builtin_amdgcn_rcpf(zparts[0]+zparts[1]+zparts[2]+zparts[3]);
      const int u = uc + (tid & 127)*2;
      const int js = (tid >> 7) << 6;
      float c0 = 0.f, c1 = 0.f;
      const unsigned short* hb = A.h_bf + (size_t)b*NS*NU;   // cached, L2-resident slice
      for (int jj = 0; jj < 64; ++jj) {
        const int j = js + jj;
        const unsigned int hv = *(const unsigned int*)(hb + (size_t)j*NU + u);
        const float wv = wsh[j];
        c0 += wv * bf2f((unsigned short)(hv & 0xffffu));
        c1 += wv * bf2f((unsigned short)(hv >> 16));
      }
      cbuf[tid][0] = c0; cbuf[tid][1] = c1;
      __syncthreads();
      if (tid < 128) {
        float cc0 = cbuf[tid][0] + cbuf[tid+128][0] + cbuf[tid+256][0] + cbuf[tid+384][0];
        float cc1 = cbuf[tid][1] + cbuf[tid+128][1] + cbuf[tid+256][1] + cbuf[tid+384][1];
        cc0 *= invZ; cc1 *= invZ;
        const int uu = uc + tid*2;
        const float* gp = A.gates + b*4096;
        floatx2 g4[4];
        cburst4d2(g4, gp + uu, gp + NU + uu, gp + 2*NU + uu, gp + 3*NU + uu);
        unsigned sout = 0;
#pragma unroll
        for (int p = 0; p < 2; ++p) {
          const float cx = p ? cc1 : cc0;
          const float iv = sigf(g4[0][p]);
          const float fv = sigf(g4[1][p]);
          const float gv = tanhf(g4[2][p]);
          const float ov = sigf(g4[3][p]);
          const float cn = fv*cx + iv*gv;
          const float sn = ov * tanhf(cn);
          sout |= ((unsigned)f2bf(sn)) << (16*p);
        }
        cst_u32((unsigned*)(A.s_bf + b*NU + uu), sout);
      }
    }
    gsync();
  }
}

// ---------------------------------------------------------------------------
extern "C" void kernel_launch(void* const* d_in, const int* in_sizes, int n_in,
                              void* d_out, int out_size, void* d_ws, size_t ws_size,
                              hipStream_t stream)
{
  const float* h   = (const float*)d_in[0];
  const float* s0  = (const float*)d_in[1];
  const float* Wy1 = (const float*)d_in[2];
  const float* by1 = (const float*)d_in[3];
  const float* Wy2 = (const float*)d_in[4];
  const float* by2 = (const float*)d_in[5];
  const float* We1 = (const float*)d_in[6];
  const float* be1 = (const float*)d_in[7];
  const float* We2 = (const float*)d_in[8];
  const float* be2 = (const float*)d_in[9];
  const float* Wf_p = (const float*)d_in[10];
  const float* bf_p = (const float*)d_in[11];
  const float* Wi_p = (const float*)d_in[12];
  const float* bi_p = (const float*)d_in[13];
  const float* Wg_p = (const float*)d_in[14];
  const float* bg_p = (const float*)d_in[15];
  const float* Wo_p = (const float*)d_in[16];
  const float* bo_p = (const float*)d_in[17];
  (void)in_sizes; (void)n_in; (void)out_size; (void)ws_size;

  char* ws = (char*)d_ws;
  size_t off = 0;
  auto alloc = [&](size_t bytes)->char*{
    char* p = ws + off; off = (off + bytes + 255) & ~(size_t)255; return p;
  };
  unsigned short* h_bf    = (unsigned short*)alloc((size_t)NB*NS*NU*2);   // 33.5 MB
  unsigned short* hproj   = (unsigned short*)alloc((size_t)NB*NS*NU*2);   // 33.5 MB
  unsigned short* tanh_all= (unsigned short*)alloc((size_t)NS*NB*NU*2);   // 33.5 MB
  unsigned short* A1_sw   = (unsigned short*)alloc((size_t)NU*2048*2);    // 4.2 MB
  unsigned short* Wbig_sw = (unsigned short*)alloc((size_t)2048*4096*2);  // 16.8 MB
  unsigned short* We1h_sw = (unsigned short*)alloc((size_t)NU*NU*2);      // 2.1 MB
  unsigned short* Wy2_sw  = (unsigned short*)alloc((size_t)NU*NT*2);      // 1.05 MB
  unsigned short* we2b = (unsigned short*)alloc(NU*2);
  unsigned short* s_bf = (unsigned short*)alloc(NB*NU*2);
  float* qbuf  = (float*)alloc((size_t)NB*NU*4);
  float* watt  = (float*)alloc((size_t)NB*NS*4);
  float* gates = (float*)alloc((size_t)NB*4096*4);
  float* bz    = (float*)alloc(2048*4);
  float* vbias = (float*)alloc(4096*4);
  int*   bar   = (int*)alloc(4096);
  // prep-only buffers aliased into regions not yet written at their use time:
  float* Mg = (float*)tanh_all;                    // 16.8 MB, dead before loop
  unsigned short* Wy2A    = hproj;                 // dead before hproj GEMM
  unsigned short* Wgtop_sw= hproj + (size_t)NU*NT; // 4 MB, dead before hproj GEMM

  hipMemsetAsync(bar, 0, 4096, stream);

  conv_h<<<dim3(4096), dim3(256), 0, stream>>>(h, h_bf, NB*NS*NU);
  conv_misc<<<dim3(2316), dim3(256), 0, stream>>>(Wy2, We2, s0, by1, be1, Wy2A, we2b, s_bf, bz);
  vbias_k<<<dim3(16), dim3(256), 0, stream>>>(by2, bi_p, bf_p, bg_p, bo_p,
                                              Wi_p, Wf_p, Wg_p, Wo_p, vbias);
  pack_b<<<dim3(1024), dim3(256), 0, stream>>>(We1, We1h_sw, 1024, 1024);   // We1_h
  pack_b<<<dim3(1024), dim3(256), 0, stream>>>(Wy2, Wy2_sw, 1024, 512);
  pack_b<<<dim3(512), dim3(256), 0, stream>>>(Wi_p, Wgtop_sw + 0*((size_t)NT*NU), 512, 1024);
  pack_b<<<dim3(512), dim3(256), 0, stream>>>(Wf_p, Wgtop_sw + 1*((size_t)NT*NU), 512, 1024);
  pack_b<<<dim3(512), dim3(256), 0, stream>>>(Wg_p, Wgtop_sw + 2*((size_t)NT*NU), 512, 1024);
  pack_b<<<dim3(512), dim3(256), 0, stream>>>(Wo_p, Wgtop_sw + 3*((size_t)NT*NU), 512, 1024);
  pack_a1<<<dim3(1024), dim3(256), 0, stream>>>(Wy1, We1, A1_sw);

  // Mg[g] = Wy2 @ W_g[:512]   (M=1024, N=1024, K=512)
  for (int g = 0; g < 4; ++g)
    gemm_sw<0><<<dim3(1024), dim3(256), 0, stream>>>(
        Wy2A, Wgtop_sw + (size_t)g*(NT*NU), Mg + (size_t)g*NU*NU,
        1024, 1024, 512, 1024, nullptr);
  pack_wbig<<<dim3(2048), dim3(256), 0, stream>>>(Mg, Wi_p, Wf_p, Wg_p, Wo_p, Wbig_sw);

  // h_proj = h @ We1_h -> bf16 (M=16384,N=1024,K=1024); overwrites Wy2A/Wgtop region
  gemm_sw<1><<<dim3(1024), dim3(256), 0, stream>>>(
      h_bf, We1h_sw, hproj, NB*NS, 1024, 1024, 1024, nullptr);

  // the 256-step recurrence: persistent kernel, 256 blocks (1/CU), 3 syncs/step
  LoopArgs la;
  la.s_bf = s_bf; la.tanh_all = tanh_all; la.A1_sw = A1_sw; la.Wbig_sw = Wbig_sw;
  la.hproj = hproj; la.h_bf = h_bf; la.we2b = we2b;
  la.qbuf = qbuf; la.watt = watt; la.gates = gates;
  la.bz = bz; la.vbias = vbias; la.be2 = be2; la.bar = bar;
  loop_kernel<<<dim3(256), dim3(512), 0, stream>>>(la);

  // Y = Tanh1_all @ Wy2 + by2, remapped (t,b)->(b,t) into d_out (M=16384,N=512,K=1024)
  gemm_sw<2><<<dim3(1024), dim3(256), 0, stream>>>(
      tanh_all, Wy2_sw, d_out, NB*NS, 512, 1024, 512, by2);
}